// Round 5
// baseline (263.373 us; speedup 1.0000x reference)
//
#include <hip/hip_runtime.h>

typedef _Float16 f16;
typedef _Float16 f16x8 __attribute__((ext_vector_type(8)));
typedef float f32x4 __attribute__((ext_vector_type(4)));

#define GLOBAL_AS __attribute__((address_space(1)))
#define LDS_AS __attribute__((address_space(3)))

__device__ __forceinline__ void async16(const void* g, void* l) {
  __builtin_amdgcn_global_load_lds((const GLOBAL_AS unsigned int*)g,
                                   (LDS_AS unsigned int*)l, 16, 0, 0);
}

// ---------------- weight conversion ----------------
// w_hidden [512][784] -> w2h f16 [512][1600] (hi pad->800 | lo*2048 pad->1600)
// w_out    [128][512] -> w2o f16 [128][512]  (hi only)
__global__ __launch_bounds__(256) void conv_w(const float* __restrict__ wh,
                                              const float* __restrict__ wo,
                                              f16* __restrict__ w2h,
                                              f16* __restrict__ w2o) {
  int idx = blockIdx.x * 256 + threadIdx.x;
  if (idx < 819200) {
    int h = idx / 1600;
    int c = idx - h * 1600;
    f16 o = (f16)0.f;
    if (c < 784) {
      o = (f16)wh[h * 784 + c];
    } else if (c >= 800 && c < 1584) {
      float x = wh[h * 784 + (c - 800)];
      f16 hi = (f16)x;
      o = (f16)((x - (float)hi) * 2048.0f);  // exact residual, scaled past denormals
    }
    w2h[idx] = o;
  } else if (idx < 819200 + 65536) {
    int j = idx - 819200;
    w2o[j] = (f16)wo[j];
  }
}

// ---------------- GEMM1: fused fp32-spike conversion + split-f16 MFMA ----------------
// c_h[32768][512] = spikes[32768][784] * (w2h_hi + 2^-11 w2h_lo)[512][800]^T.
// A staged via VGPR cvt + ds_write_b128 (spikes {0,1} -> f16 exact), B via async16.
// XOR-swizzled LDS (granule p = g ^ (r&7)); wave64 b128 r/w = 8 dwords/bank = floor.
// 1-D grid 1024, mapped so the 4 n-blocks of an m-tile share an XCD L2 (b%8 equal).
__global__ __launch_bounds__(256, 2) void gemm1(const float* __restrict__ SP,
                                                const f16* __restrict__ B,
                                                float* __restrict__ C) {
  __shared__ f16 lds_a[128 * 64];
  __shared__ f16 lds_bh[128 * 64];
  __shared__ f16 lds_bl[128 * 64];
  const int t = threadIdx.x;
  const int lane = t & 63;
  const int wave = t >> 6;
  const int b = blockIdx.x;
  const int by = (b & 7) + 8 * (b >> 5);
  const int bx = (b >> 3) & 3;
  const int m0 = by * 128;
  const int n0 = bx * 128;
  const int wm = (wave >> 1) * 64;
  const int wn = (wave & 1) * 64;
  const int row = lane & 15;
  const int quad = lane >> 4;

  const int r2 = t >> 1;   // A-staging row (0..127)
  const int half = t & 1;  // which 32-col half
  const float* a_row = SP + (size_t)(m0 + r2) * 784;

  f32x4 acch[4][4] = {};
  f32x4 accl[4][4] = {};

  for (int c = 0; c < 12; ++c) {
    const int k0 = c * 64;
#pragma unroll
    for (int s = 0; s < 4; ++s) {
      const int j = t + s * 256;
      const int r = j >> 3;
      const int g = (j & 7) ^ (r & 7);
      async16(B + (n0 + r) * 1600 + k0 + g * 8, &lds_bh[j * 8]);
      async16(B + (n0 + r) * 1600 + 800 + k0 + g * 8, &lds_bl[j * 8]);
    }
#pragma unroll
    for (int gi = 0; gi < 4; ++gi) {
      const int g = half * 4 + gi;
      const float* src = a_row + k0 + g * 8;
      float4 x = *(const float4*)src;
      float4 y = *(const float4*)(src + 4);
      f16x8 h;
      h[0] = (f16)x.x; h[1] = (f16)x.y; h[2] = (f16)x.z; h[3] = (f16)x.w;
      h[4] = (f16)y.x; h[5] = (f16)y.y; h[6] = (f16)y.z; h[7] = (f16)y.w;
      *(f16x8*)&lds_a[r2 * 64 + ((g ^ (r2 & 7)) * 8)] = h;
    }
    __syncthreads();
#pragma unroll
    for (int ks = 0; ks < 2; ++ks) {
      f16x8 af[4], bh[4], bl[4];
#pragma unroll
      for (int tm = 0; tm < 4; ++tm) {
        const int ra = wm + tm * 16 + row;
        const int p = (ks * 4 + quad) ^ (ra & 7);
        af[tm] = *(const f16x8*)&lds_a[ra * 64 + p * 8];
      }
#pragma unroll
      for (int tn = 0; tn < 4; ++tn) {
        const int rb = wn + tn * 16 + row;
        const int p = (ks * 4 + quad) ^ (rb & 7);
        bh[tn] = *(const f16x8*)&lds_bh[rb * 64 + p * 8];
        bl[tn] = *(const f16x8*)&lds_bl[rb * 64 + p * 8];
      }
#pragma unroll
      for (int tm = 0; tm < 4; ++tm)
#pragma unroll
        for (int tn = 0; tn < 4; ++tn) {
          acch[tm][tn] =
              __builtin_amdgcn_mfma_f32_16x16x32_f16(af[tm], bh[tn], acch[tm][tn], 0, 0, 0);
          accl[tm][tn] =
              __builtin_amdgcn_mfma_f32_16x16x32_f16(af[tm], bl[tn], accl[tm][tn], 0, 0, 0);
        }
    }
    __syncthreads();
  }

  {  // K tail: cols 768..799 (spikes valid to 783; rest zero)
#pragma unroll
    for (int s = 0; s < 2; ++s) {
      const int j = t + s * 256;
      const int r = j >> 2;
      const int g = (j & 3) ^ (r & 3);
      async16(B + (n0 + r) * 1600 + 768 + g * 8, &lds_bh[j * 8]);
      async16(B + (n0 + r) * 1600 + 800 + 768 + g * 8, &lds_bl[j * 8]);
    }
#pragma unroll
    for (int gi = 0; gi < 2; ++gi) {
      const int g = half * 2 + gi;  // 0..3; g>=2 -> cols 784..799 = zero pad
      f16x8 h = {};
      if (g < 2) {
        const float* src = a_row + 768 + g * 8;
        float4 x = *(const float4*)src;
        float4 y = *(const float4*)(src + 4);
        h[0] = (f16)x.x; h[1] = (f16)x.y; h[2] = (f16)x.z; h[3] = (f16)x.w;
        h[4] = (f16)y.x; h[5] = (f16)y.y; h[6] = (f16)y.z; h[7] = (f16)y.w;
      }
      *(f16x8*)&lds_a[r2 * 32 + ((g ^ (r2 & 3)) * 8)] = h;
    }
    __syncthreads();
    f16x8 af[4], bh[4], bl[4];
#pragma unroll
    for (int tm = 0; tm < 4; ++tm) {
      const int ra = wm + tm * 16 + row;
      const int p = quad ^ (ra & 3);
      af[tm] = *(const f16x8*)&lds_a[ra * 32 + p * 8];
    }
#pragma unroll
    for (int tn = 0; tn < 4; ++tn) {
      const int rb = wn + tn * 16 + row;
      const int p = quad ^ (rb & 3);
      bh[tn] = *(const f16x8*)&lds_bh[rb * 32 + p * 8];
      bl[tn] = *(const f16x8*)&lds_bl[rb * 32 + p * 8];
    }
#pragma unroll
    for (int tm = 0; tm < 4; ++tm)
#pragma unroll
      for (int tn = 0; tn < 4; ++tn) {
        acch[tm][tn] =
            __builtin_amdgcn_mfma_f32_16x16x32_f16(af[tm], bh[tn], acch[tm][tn], 0, 0, 0);
        accl[tm][tn] =
            __builtin_amdgcn_mfma_f32_16x16x32_f16(af[tm], bl[tn], accl[tm][tn], 0, 0, 0);
      }
  }

  // C/D layout: col = lane&15, row = quad*4 + r
#pragma unroll
  for (int tm = 0; tm < 4; ++tm)
#pragma unroll
    for (int tn = 0; tn < 4; ++tn)
#pragma unroll
      for (int r = 0; r < 4; ++r) {
        const int mm = m0 + wm + tm * 16 + quad * 4 + r;
        const int nn = n0 + wn + tn * 16 + row;
        C[(size_t)mm * 512 + nn] = acch[tm][tn][r] + 4.8828125e-4f * accl[tm][tn][r];
      }
}

// ---------------- GEMM2: s_h * w_out^T, f16 single-plane, K-split x2 ----------------
__global__ __launch_bounds__(256, 2) void gemm2(const f16* __restrict__ A,
                                                const f16* __restrict__ B,
                                                float* __restrict__ C) {
  __shared__ f16 lds_a[128 * 64];
  __shared__ f16 lds_b[128 * 64];
  const int t = threadIdx.x;
  const int lane = t & 63;
  const int wave = t >> 6;
  const int m0 = blockIdx.y * 128;
  const int kb = blockIdx.x * 256;
  float* Cp = C + (size_t)blockIdx.x * 32768 * 128;
  const int wm = (wave >> 1) * 64;
  const int wn = (wave & 1) * 64;
  const int row = lane & 15;
  const int quad = lane >> 4;
  f32x4 acc[4][4] = {};
  for (int c = 0; c < 4; ++c) {
    const int k0 = kb + c * 64;
#pragma unroll
    for (int s = 0; s < 4; ++s) {
      const int j = t + s * 256;
      const int r = j >> 3;
      const int g = (j & 7) ^ (r & 7);
      async16(A + (m0 + r) * 512 + k0 + g * 8, &lds_a[j * 8]);
      async16(B + r * 512 + k0 + g * 8, &lds_b[j * 8]);
    }
    __syncthreads();
#pragma unroll
    for (int ks = 0; ks < 2; ++ks) {
      f16x8 af[4], bf[4];
#pragma unroll
      for (int tm = 0; tm < 4; ++tm) {
        const int ra = wm + tm * 16 + row;
        const int p = (ks * 4 + quad) ^ (ra & 7);
        af[tm] = *(const f16x8*)&lds_a[ra * 64 + p * 8];
      }
#pragma unroll
      for (int tn = 0; tn < 4; ++tn) {
        const int rb = wn + tn * 16 + row;
        const int p = (ks * 4 + quad) ^ (rb & 7);
        bf[tn] = *(const f16x8*)&lds_b[rb * 64 + p * 8];
      }
#pragma unroll
      for (int tm = 0; tm < 4; ++tm)
#pragma unroll
        for (int tn = 0; tn < 4; ++tn)
          acc[tm][tn] =
              __builtin_amdgcn_mfma_f32_16x16x32_f16(af[tm], bf[tn], acc[tm][tn], 0, 0, 0);
    }
    __syncthreads();
  }
#pragma unroll
  for (int tm = 0; tm < 4; ++tm)
#pragma unroll
    for (int tn = 0; tn < 4; ++tn)
#pragma unroll
      for (int r = 0; r < 4; ++r) {
        const int mm = m0 + wm + tm * 16 + quad * 4 + r;
        const int nn = wn + tn * 16 + row;
        Cp[(size_t)mm * 128 + nn] = acc[tm][tn][r];
      }
}

// ---------------- CUBA LIF scan (double-buffered batches of 8) ----------------
__global__ __launch_bounds__(256) void lif_scan(const float* __restrict__ ch,
                                                f16* __restrict__ sh) {
  const int n = blockIdx.x * 256 + threadIdx.x;  // 65536 neurons
  float xa[8], xb[8];
#pragma unroll
  for (int j = 0; j < 8; ++j) xa[j] = ch[j * 65536 + n];
  float v = 0.f, cur = 0.f;
  for (int c = 0; c < 32; ++c) {
    const int nc = (c + 1) & 31;  // wrap: chunk-0 reload at c=31 is dead, L2-hot
#pragma unroll
    for (int j = 0; j < 8; ++j) xb[j] = ch[(nc * 8 + j) * 65536 + n];
#pragma unroll
    for (int j = 0; j < 8; ++j) {
      const int t = c * 8 + j;
      float x = xa[j];
      v = v + 0.16666667f * (cur - v);  // v += dt*tau_mem_inv*(-v+i), old i
      cur = 0.8333333f * cur + x;       // i = i*(1-dt*tau_syn_inv) + x
      bool z = v > 1.0f;
      sh[t * 65536 + n] = z ? (f16)1.f : (f16)0.f;
      v = z ? 0.f : v;
    }
#pragma unroll
    for (int j = 0; j < 8; ++j) xa[j] = xb[j];
  }
}

// ---------------- CUBA LI scan, 4-way T-segmented ----------------
// LI is linear; state decays (5/6)^d. Segments warm-run the previous 64 steps
// from zero state (err < 4e-3 rel), then emit 64 outputs. Sums K-split streams.
__global__ __launch_bounds__(256) void li_scan_seg(const float* __restrict__ coA,
                                                   const float* __restrict__ coB,
                                                   float* __restrict__ out) {
  const int tid = blockIdx.x * 256 + threadIdx.x;  // 65536
  const int n = tid & 16383;
  const int seg = tid >> 14;  // 0..3
  const int t0 = seg * 64;
  float v = 0.f, cur = 0.f;
  float xa[8], xb[8];
  if (seg) {
    const int w0 = t0 - 64;
#pragma unroll
    for (int j = 0; j < 8; ++j)
      xa[j] = coA[(w0 + j) * 16384 + n] + coB[(w0 + j) * 16384 + n];
    for (int c = 0; c < 8; ++c) {
      const int nb = w0 + (c + 1) * 8;  // c==7 prefetches t0..t0+7
#pragma unroll
      for (int j = 0; j < 8; ++j)
        xb[j] = coA[(nb + j) * 16384 + n] + coB[(nb + j) * 16384 + n];
#pragma unroll
      for (int j = 0; j < 8; ++j) {
        v = v + 0.16666667f * (cur - v);
        cur = 0.8333333f * cur + xa[j];
      }
#pragma unroll
      for (int j = 0; j < 8; ++j) xa[j] = xb[j];
    }
  } else {
#pragma unroll
    for (int j = 0; j < 8; ++j) xa[j] = coA[j * 16384 + n] + coB[j * 16384 + n];
  }
  for (int c = 0; c < 8; ++c) {
    if (c < 7) {
      const int nb = t0 + (c + 1) * 8;
#pragma unroll
      for (int j = 0; j < 8; ++j)
        xb[j] = coA[(nb + j) * 16384 + n] + coB[(nb + j) * 16384 + n];
    }
#pragma unroll
    for (int j = 0; j < 8; ++j) {
      const int t = t0 + c * 8 + j;
      v = v + 0.16666667f * (cur - v);
      cur = 0.8333333f * cur + xa[j];
      out[t * 16384 + n] = v;
    }
#pragma unroll
    for (int j = 0; j < 8; ++j) xa[j] = xb[j];
  }
}

// ---------------- launch ----------------
extern "C" void kernel_launch(void* const* d_in, const int* in_sizes, int n_in,
                              void* d_out, int out_size, void* d_ws, size_t ws_size,
                              hipStream_t stream) {
  const float* spikes = (const float*)d_in[0];    // [256][128][784]
  const float* w_hidden = (const float*)d_in[1];  // [512][784]
  const float* w_out = (const float*)d_in[2];     // [128][512]
  float* out = (float*)d_out;                     // [256][128][128]

  char* ws = (char*)d_ws;
  // layout (bytes):
  //   coA|coB [2][32768][128] f32 : 33,554,432  (at offset 0)
  //   w2h  [512][1600]  f16 :  1,638,400        (at 52,428,800)
  //   c_h  [32768][512] f32 : 67,108,864
  //   s_h  [32768][512] f16 : 33,554,432
  //   w2o  [128][512]   f16 :    131,072
  float* coA = (float*)ws;
  float* coB = (float*)(ws + 16777216);
  f16* w2h = (f16*)(ws + 52428800);
  float* c_h = (float*)(ws + 52428800 + 1638400);
  f16* s_h = (f16*)(ws + 52428800 + 1638400 + 67108864);
  f16* w2o = (f16*)(ws + 52428800 + 1638400 + 67108864 + 33554432);

  conv_w<<<3456, 256, 0, stream>>>(w_hidden, w_out, w2h, w2o);

  // GEMM1 (fused spike conversion): c_h = spikes * w2h^T, K = 12*64 + 32
  gemm1<<<1024, 256, 0, stream>>>(spikes, w2h, c_h);

  lif_scan<<<256, 256, 0, stream>>>(c_h, s_h);

  // GEMM2: co{A,B} = s_h * w2o^T, K-split 2x256
  gemm2<<<dim3(2, 256), 256, 0, stream>>>(s_h, w2o, coA);

  li_scan_seg<<<256, 256, 0, stream>>>(coA, coB, out);
}

// Round 6
// 258.577 us; speedup vs baseline: 1.0185x; 1.0185x over previous
//
#include <hip/hip_runtime.h>

typedef _Float16 f16;
typedef _Float16 f16x8 __attribute__((ext_vector_type(8)));
typedef float f32x4 __attribute__((ext_vector_type(4)));

#define GLOBAL_AS __attribute__((address_space(1)))
#define LDS_AS __attribute__((address_space(3)))

__device__ __forceinline__ void async16(const void* g, void* l) {
  __builtin_amdgcn_global_load_lds((const GLOBAL_AS unsigned int*)g,
                                   (LDS_AS unsigned int*)l, 16, 0, 0);
}

// ---------------- weight conversion ----------------
// w_hidden [512][784] -> w2h f16 [512][1600] (hi pad->800 | lo*2048 pad->1600)
// w_out    [128][512] -> w2o f16 [128][512]  (hi only)
__global__ __launch_bounds__(256) void conv_w(const float* __restrict__ wh,
                                              const float* __restrict__ wo,
                                              f16* __restrict__ w2h,
                                              f16* __restrict__ w2o) {
  int idx = blockIdx.x * 256 + threadIdx.x;
  if (idx < 819200) {
    int h = idx / 1600;
    int c = idx - h * 1600;
    f16 o = (f16)0.f;
    if (c < 784) {
      o = (f16)wh[h * 784 + c];
    } else if (c >= 800 && c < 1584) {
      float x = wh[h * 784 + (c - 800)];
      f16 hi = (f16)x;
      o = (f16)((x - (float)hi) * 2048.0f);  // exact residual, scaled past denormals
    }
    w2h[idx] = o;
  } else if (idx < 819200 + 65536) {
    int j = idx - 819200;
    w2o[j] = (f16)wo[j];
  }
}

// ---------------- GEMM1: fused spike conversion + split-f16 MFMA, A-prefetch ----------
// c_h[32768][512] = spikes[32768][784] * (w2h_hi + 2^-11 w2h_lo)[512][800]^T.
// A path: spike fp32 loads for chunk c+1 are ISSUED in the compute region of
// chunk c (hidden behind MFMA; drained by the end-of-iteration barrier) and
// consumed (cvt+ds_write, zero-wait) at the top of c+1. B via async16.
// XOR-swizzled LDS (granule p = g ^ (r&7)). 1-D grid 1024, XCD-swizzled.
__global__ __launch_bounds__(256, 2) void gemm1(const float* __restrict__ SP,
                                                const f16* __restrict__ B,
                                                float* __restrict__ C) {
  __shared__ f16 lds_a[128 * 64];
  __shared__ f16 lds_bh[128 * 64];
  __shared__ f16 lds_bl[128 * 64];
  const int t = threadIdx.x;
  const int lane = t & 63;
  const int wave = t >> 6;
  const int b = blockIdx.x;
  const int by = (b & 7) + 8 * (b >> 5);
  const int bx = (b >> 3) & 3;
  const int m0 = by * 128;
  const int n0 = bx * 128;
  const int wm = (wave >> 1) * 64;
  const int wn = (wave & 1) * 64;
  const int row = lane & 15;
  const int quad = lane >> 4;

  const int r2 = t >> 1;   // A-staging row (0..127)
  const int half = t & 1;  // which 32-col half
  const float* a_row = SP + (size_t)(m0 + r2) * 784;

  f32x4 acch[4][4] = {};
  f32x4 accl[4][4] = {};

  float4 pre[8];  // prefetched spike fp32s: 4 granules x 2 float4
#pragma unroll
  for (int gi = 0; gi < 4; ++gi) {
    const int g = half * 4 + gi;
    pre[2 * gi] = *(const float4*)(a_row + g * 8);
    pre[2 * gi + 1] = *(const float4*)(a_row + g * 8 + 4);
  }

  for (int c = 0; c < 12; ++c) {
    const int k0 = c * 64;
    // B staging first (gets the async queue moving), then A cvt+write (no waits).
#pragma unroll
    for (int s = 0; s < 4; ++s) {
      const int j = t + s * 256;
      const int r = j >> 3;
      const int g = (j & 7) ^ (r & 7);
      async16(B + (n0 + r) * 1600 + k0 + g * 8, &lds_bh[j * 8]);
      async16(B + (n0 + r) * 1600 + 800 + k0 + g * 8, &lds_bl[j * 8]);
    }
#pragma unroll
    for (int gi = 0; gi < 4; ++gi) {
      const int g = half * 4 + gi;
      float4 x = pre[2 * gi], y = pre[2 * gi + 1];
      f16x8 h;
      h[0] = (f16)x.x; h[1] = (f16)x.y; h[2] = (f16)x.z; h[3] = (f16)x.w;
      h[4] = (f16)y.x; h[5] = (f16)y.y; h[6] = (f16)y.z; h[7] = (f16)y.w;
      *(f16x8*)&lds_a[r2 * 64 + ((g ^ (r2 & 7)) * 8)] = h;
    }
    __syncthreads();  // barrier1: drains B async16

    // ---- compute region: issue next-chunk A prefetch, then MFMA ----
    if (c < 11) {
      const int k1 = (c + 1) * 64;
#pragma unroll
      for (int gi = 0; gi < 4; ++gi) {
        const int g = half * 4 + gi;
        pre[2 * gi] = *(const float4*)(a_row + k1 + g * 8);
        pre[2 * gi + 1] = *(const float4*)(a_row + k1 + g * 8 + 4);
      }
    } else {
      // tail granules: 32 cols at 768; g2 = half*2+gi (0..3), cols >=784 are pad
      const float4 z = {0.f, 0.f, 0.f, 0.f};
#pragma unroll
      for (int gi = 0; gi < 2; ++gi) {
        const int g2 = half * 2 + gi;
        if (g2 < 2) {
          pre[2 * gi] = *(const float4*)(a_row + 768 + g2 * 8);
          pre[2 * gi + 1] = *(const float4*)(a_row + 768 + g2 * 8 + 4);
        } else {
          pre[2 * gi] = z;
          pre[2 * gi + 1] = z;
        }
      }
    }
#pragma unroll
    for (int ks = 0; ks < 2; ++ks) {
      f16x8 af[4], bh[4], bl[4];
#pragma unroll
      for (int tm = 0; tm < 4; ++tm) {
        const int ra = wm + tm * 16 + row;
        const int p = (ks * 4 + quad) ^ (ra & 7);
        af[tm] = *(const f16x8*)&lds_a[ra * 64 + p * 8];
      }
#pragma unroll
      for (int tn = 0; tn < 4; ++tn) {
        const int rb = wn + tn * 16 + row;
        const int p = (ks * 4 + quad) ^ (rb & 7);
        bh[tn] = *(const f16x8*)&lds_bh[rb * 64 + p * 8];
        bl[tn] = *(const f16x8*)&lds_bl[rb * 64 + p * 8];
      }
#pragma unroll
      for (int tm = 0; tm < 4; ++tm)
#pragma unroll
        for (int tn = 0; tn < 4; ++tn) {
          acch[tm][tn] =
              __builtin_amdgcn_mfma_f32_16x16x32_f16(af[tm], bh[tn], acch[tm][tn], 0, 0, 0);
          accl[tm][tn] =
              __builtin_amdgcn_mfma_f32_16x16x32_f16(af[tm], bl[tn], accl[tm][tn], 0, 0, 0);
        }
    }
    __syncthreads();  // barrier2: protects lds_a rewrite; drains A prefetch loads
  }

  {  // K tail: cols 768..799, 32-wide chunk (granule swizzle &3)
#pragma unroll
    for (int s = 0; s < 2; ++s) {
      const int j = t + s * 256;
      const int r = j >> 2;
      const int g = (j & 3) ^ (r & 3);
      async16(B + (n0 + r) * 1600 + 768 + g * 8, &lds_bh[j * 8]);
      async16(B + (n0 + r) * 1600 + 800 + 768 + g * 8, &lds_bl[j * 8]);
    }
#pragma unroll
    for (int gi = 0; gi < 2; ++gi) {
      const int g2 = half * 2 + gi;
      float4 x = pre[2 * gi], y = pre[2 * gi + 1];
      f16x8 h;
      h[0] = (f16)x.x; h[1] = (f16)x.y; h[2] = (f16)x.z; h[3] = (f16)x.w;
      h[4] = (f16)y.x; h[5] = (f16)y.y; h[6] = (f16)y.z; h[7] = (f16)y.w;
      *(f16x8*)&lds_a[r2 * 32 + ((g2 ^ (r2 & 3)) * 8)] = h;
    }
    __syncthreads();
    f16x8 af[4], bh[4], bl[4];
#pragma unroll
    for (int tm = 0; tm < 4; ++tm) {
      const int ra = wm + tm * 16 + row;
      const int p = quad ^ (ra & 3);
      af[tm] = *(const f16x8*)&lds_a[ra * 32 + p * 8];
    }
#pragma unroll
    for (int tn = 0; tn < 4; ++tn) {
      const int rb = wn + tn * 16 + row;
      const int p = quad ^ (rb & 3);
      bh[tn] = *(const f16x8*)&lds_bh[rb * 32 + p * 8];
      bl[tn] = *(const f16x8*)&lds_bl[rb * 32 + p * 8];
    }
#pragma unroll
    for (int tm = 0; tm < 4; ++tm)
#pragma unroll
      for (int tn = 0; tn < 4; ++tn) {
        acch[tm][tn] =
            __builtin_amdgcn_mfma_f32_16x16x32_f16(af[tm], bh[tn], acch[tm][tn], 0, 0, 0);
        accl[tm][tn] =
            __builtin_amdgcn_mfma_f32_16x16x32_f16(af[tm], bl[tn], accl[tm][tn], 0, 0, 0);
      }
  }

  // C/D layout: col = lane&15, row = quad*4 + r
#pragma unroll
  for (int tm = 0; tm < 4; ++tm)
#pragma unroll
    for (int tn = 0; tn < 4; ++tn)
#pragma unroll
      for (int r = 0; r < 4; ++r) {
        const int mm = m0 + wm + tm * 16 + quad * 4 + r;
        const int nn = n0 + wn + tn * 16 + row;
        C[(size_t)mm * 512 + nn] = acch[tm][tn][r] + 4.8828125e-4f * accl[tm][tn][r];
      }
}

// ---------------- GEMM2: s_h * w_out^T, f16 single-plane, K-split x2 ----------------
__global__ __launch_bounds__(256, 2) void gemm2(const f16* __restrict__ A,
                                                const f16* __restrict__ B,
                                                float* __restrict__ C) {
  __shared__ f16 lds_a[128 * 64];
  __shared__ f16 lds_b[128 * 64];
  const int t = threadIdx.x;
  const int lane = t & 63;
  const int wave = t >> 6;
  const int m0 = blockIdx.y * 128;
  const int kb = blockIdx.x * 256;
  float* Cp = C + (size_t)blockIdx.x * 32768 * 128;
  const int wm = (wave >> 1) * 64;
  const int wn = (wave & 1) * 64;
  const int row = lane & 15;
  const int quad = lane >> 4;
  f32x4 acc[4][4] = {};
  for (int c = 0; c < 4; ++c) {
    const int k0 = kb + c * 64;
#pragma unroll
    for (int s = 0; s < 4; ++s) {
      const int j = t + s * 256;
      const int r = j >> 3;
      const int g = (j & 7) ^ (r & 7);
      async16(A + (m0 + r) * 512 + k0 + g * 8, &lds_a[j * 8]);
      async16(B + r * 512 + k0 + g * 8, &lds_b[j * 8]);
    }
    __syncthreads();
#pragma unroll
    for (int ks = 0; ks < 2; ++ks) {
      f16x8 af[4], bf[4];
#pragma unroll
      for (int tm = 0; tm < 4; ++tm) {
        const int ra = wm + tm * 16 + row;
        const int p = (ks * 4 + quad) ^ (ra & 7);
        af[tm] = *(const f16x8*)&lds_a[ra * 64 + p * 8];
      }
#pragma unroll
      for (int tn = 0; tn < 4; ++tn) {
        const int rb = wn + tn * 16 + row;
        const int p = (ks * 4 + quad) ^ (rb & 7);
        bf[tn] = *(const f16x8*)&lds_b[rb * 64 + p * 8];
      }
#pragma unroll
      for (int tm = 0; tm < 4; ++tm)
#pragma unroll
        for (int tn = 0; tn < 4; ++tn)
          acc[tm][tn] =
              __builtin_amdgcn_mfma_f32_16x16x32_f16(af[tm], bf[tn], acc[tm][tn], 0, 0, 0);
    }
    __syncthreads();
  }
#pragma unroll
  for (int tm = 0; tm < 4; ++tm)
#pragma unroll
    for (int tn = 0; tn < 4; ++tn)
#pragma unroll
      for (int r = 0; r < 4; ++r) {
        const int mm = m0 + wm + tm * 16 + quad * 4 + r;
        const int nn = wn + tn * 16 + row;
        Cp[(size_t)mm * 128 + nn] = acc[tm][tn][r];
      }
}

// ---------------- CUBA LIF scan (double-buffered batches of 8) ----------------
__global__ __launch_bounds__(256) void lif_scan(const float* __restrict__ ch,
                                                f16* __restrict__ sh) {
  const int n = blockIdx.x * 256 + threadIdx.x;  // 65536 neurons
  float xa[8], xb[8];
#pragma unroll
  for (int j = 0; j < 8; ++j) xa[j] = ch[j * 65536 + n];
  float v = 0.f, cur = 0.f;
  for (int c = 0; c < 32; ++c) {
    const int nc = (c + 1) & 31;  // wrap: chunk-0 reload at c=31 is dead, L2-hot
#pragma unroll
    for (int j = 0; j < 8; ++j) xb[j] = ch[(nc * 8 + j) * 65536 + n];
#pragma unroll
    for (int j = 0; j < 8; ++j) {
      const int t = c * 8 + j;
      float x = xa[j];
      v = v + 0.16666667f * (cur - v);  // v += dt*tau_mem_inv*(-v+i), old i
      cur = 0.8333333f * cur + x;       // i = i*(1-dt*tau_syn_inv) + x
      bool z = v > 1.0f;
      sh[t * 65536 + n] = z ? (f16)1.f : (f16)0.f;
      v = z ? 0.f : v;
    }
#pragma unroll
    for (int j = 0; j < 8; ++j) xa[j] = xb[j];
  }
}

// ---------------- CUBA LI scan, 4-way T-segmented ----------------
// LI is linear; state decays (5/6)^d. Segments warm-run the previous 64 steps
// from zero state (err < 4e-3 rel), then emit 64 outputs. Sums K-split streams.
__global__ __launch_bounds__(256) void li_scan_seg(const float* __restrict__ coA,
                                                   const float* __restrict__ coB,
                                                   float* __restrict__ out) {
  const int tid = blockIdx.x * 256 + threadIdx.x;  // 65536
  const int n = tid & 16383;
  const int seg = tid >> 14;  // 0..3
  const int t0 = seg * 64;
  float v = 0.f, cur = 0.f;
  float xa[8], xb[8];
  if (seg) {
    const int w0 = t0 - 64;
#pragma unroll
    for (int j = 0; j < 8; ++j)
      xa[j] = coA[(w0 + j) * 16384 + n] + coB[(w0 + j) * 16384 + n];
    for (int c = 0; c < 8; ++c) {
      const int nb = w0 + (c + 1) * 8;  // c==7 prefetches t0..t0+7
#pragma unroll
      for (int j = 0; j < 8; ++j)
        xb[j] = coA[(nb + j) * 16384 + n] + coB[(nb + j) * 16384 + n];
#pragma unroll
      for (int j = 0; j < 8; ++j) {
        v = v + 0.16666667f * (cur - v);
        cur = 0.8333333f * cur + xa[j];
      }
#pragma unroll
      for (int j = 0; j < 8; ++j) xa[j] = xb[j];
    }
  } else {
#pragma unroll
    for (int j = 0; j < 8; ++j) xa[j] = coA[j * 16384 + n] + coB[j * 16384 + n];
  }
  for (int c = 0; c < 8; ++c) {
    if (c < 7) {
      const int nb = t0 + (c + 1) * 8;
#pragma unroll
      for (int j = 0; j < 8; ++j)
        xb[j] = coA[(nb + j) * 16384 + n] + coB[(nb + j) * 16384 + n];
    }
#pragma unroll
    for (int j = 0; j < 8; ++j) {
      const int t = t0 + c * 8 + j;
      v = v + 0.16666667f * (cur - v);
      cur = 0.8333333f * cur + xa[j];
      out[t * 16384 + n] = v;
    }
#pragma unroll
    for (int j = 0; j < 8; ++j) xa[j] = xb[j];
  }
}

// ---------------- launch ----------------
extern "C" void kernel_launch(void* const* d_in, const int* in_sizes, int n_in,
                              void* d_out, int out_size, void* d_ws, size_t ws_size,
                              hipStream_t stream) {
  const float* spikes = (const float*)d_in[0];    // [256][128][784]
  const float* w_hidden = (const float*)d_in[1];  // [512][784]
  const float* w_out = (const float*)d_in[2];     // [128][512]
  float* out = (float*)d_out;                     // [256][128][128]

  char* ws = (char*)d_ws;
  // layout (bytes):
  //   coA|coB [2][32768][128] f32 : 33,554,432  (at offset 0)
  //   w2h  [512][1600]  f16 :  1,638,400        (at 52,428,800)
  //   c_h  [32768][512] f32 : 67,108,864
  //   s_h  [32768][512] f16 : 33,554,432
  //   w2o  [128][512]   f16 :    131,072
  float* coA = (float*)ws;
  float* coB = (float*)(ws + 16777216);
  f16* w2h = (f16*)(ws + 52428800);
  float* c_h = (float*)(ws + 52428800 + 1638400);
  f16* s_h = (f16*)(ws + 52428800 + 1638400 + 67108864);
  f16* w2o = (f16*)(ws + 52428800 + 1638400 + 67108864 + 33554432);

  conv_w<<<3456, 256, 0, stream>>>(w_hidden, w_out, w2h, w2o);

  // GEMM1 (fused spike conversion, A reg-prefetch): c_h = spikes * w2h^T
  gemm1<<<1024, 256, 0, stream>>>(spikes, w2h, c_h);

  lif_scan<<<256, 256, 0, stream>>>(c_h, s_h);

  // GEMM2: co{A,B} = s_h * w2o^T, K-split 2x256
  gemm2<<<dim3(2, 256), 256, 0, stream>>>(s_h, w2o, coA);

  li_scan_seg<<<256, 256, 0, stream>>>(coA, coB, out);
}